// Round 8
// baseline (413.075 us; speedup 1.0000x reference)
//
#include <hip/hip_runtime.h>

#define NN 50000
#define DIN 128
#define DH  128
#define DOUT 40
#define BN_EPS 1e-5f

__device__ __forceinline__ void atomAddF(float* p, float v) {
  unsafeAtomicAdd(p, v);   // native global_atomic_add_f32 on gfx950
}

// 1. int in-degree histogram over dst (self-loop folded in later)
__global__ void k_deg(const int* __restrict__ dst, int* __restrict__ deg, int E) {
  int e = blockIdx.x * blockDim.x + threadIdx.x;
  if (e < E) atomicAdd(&deg[dst[e]], 1);
}

// 2. CSR offsets via wave-aggregated atomic counter. Segment ORDER in csr is
//    irrelevant (k_fill assigns slots atomically anyway) and does not affect
//    any floating-point summation order.
__global__ void k_off(const int* __restrict__ deg, int* __restrict__ off,
                      int* __restrict__ cur, float* __restrict__ dinv,
                      int* __restrict__ counter) {
  int i = blockIdx.x * 256 + threadIdx.x;
  int lane = threadIdx.x & 63;
  int d = (i < NN) ? deg[i] : 0;
  int pre = d;
#pragma unroll
  for (int o = 1; o < 64; o <<= 1) {
    int v = __shfl_up(pre, o);
    if (lane >= o) pre += v;
  }
  int tot = __shfl(pre, 63);            // wave total
  int base = 0;
  if (lane == 63) base = atomicAdd(counter, tot);
  base = __shfl(base, 63);
  int o0 = base + pre - d;              // exclusive within wave
  if (i < NN) {
    off[i] = o0; cur[i] = o0;
    dinv[i] = rsqrtf((float)d + 1.0f);
  }
}

// 3. CSR fill: group src indices by dst
__global__ void k_fill(const int* __restrict__ src, const int* __restrict__ dst,
                       int* __restrict__ cur, int* __restrict__ csr, int E) {
  int e = blockIdx.x * blockDim.x + threadIdx.x;
  if (e >= E) return;
  int pos = atomicAdd(&cur[dst[e]], 1);
  csr[pos] = src[e];
}

// 4. Y1[i][j] = dinv[i] * sum_k X[i][k] * W1[k][j]
//    register-blocked: 8 rows x 4 cols per thread, float4 loads both sides.
__global__ __launch_bounds__(256) void k_gemm1(const float* __restrict__ X,
                                               const float* __restrict__ W,
                                               const float* __restrict__ dinv,
                                               float* __restrict__ Y) {
  int t = threadIdx.x;
  int tx = t & 31;          // col quad 0..31 -> c0 = tx*4
  int ty = t >> 5;          // 0..7 -> 8 rows each
  int r0 = blockIdx.x * 64 + ty * 8;
  int c0 = tx * 4;
  const float4* W4 = (const float4*)W;   // quad index = k*32 + tx

  const float* xp[8];
#pragma unroll
  for (int r = 0; r < 8; ++r) {
    int row = r0 + r;
    if (row >= NN) row = NN - 1;         // clamp: safe load, store guarded
    xp[r] = X + (size_t)row * DIN;
  }

  float acc[8][4] = {};
  for (int k = 0; k < DIN; k += 4) {
    float4 w0 = W4[(k + 0) * 32 + tx];
    float4 w1 = W4[(k + 1) * 32 + tx];
    float4 w2 = W4[(k + 2) * 32 + tx];
    float4 w3 = W4[(k + 3) * 32 + tx];
#pragma unroll
    for (int r = 0; r < 8; ++r) {
      float4 xv = *(const float4*)(xp[r] + k);
      acc[r][0] = fmaf(xv.x, w0.x, fmaf(xv.y, w1.x, fmaf(xv.z, w2.x, fmaf(xv.w, w3.x, acc[r][0]))));
      acc[r][1] = fmaf(xv.x, w0.y, fmaf(xv.y, w1.y, fmaf(xv.z, w2.y, fmaf(xv.w, w3.y, acc[r][1]))));
      acc[r][2] = fmaf(xv.x, w0.z, fmaf(xv.y, w1.z, fmaf(xv.z, w2.z, fmaf(xv.w, w3.z, acc[r][2]))));
      acc[r][3] = fmaf(xv.x, w0.w, fmaf(xv.y, w1.w, fmaf(xv.z, w2.w, fmaf(xv.w, w3.w, acc[r][3]))));
    }
  }
#pragma unroll
  for (int r = 0; r < 8; ++r) {
    int row = r0 + r;
    if (row < NN) {
      float dv = dinv[row];
      *(float4*)(Y + (size_t)row * DH + c0) =
          make_float4(acc[r][0] * dv, acc[r][1] * dv, acc[r][2] * dv, acc[r][3] * dv);
    }
  }
}

// 5. pull-mode aggregation layer1 + finalize + fused BN column stats.
//    Wave per node. CSR walk forced onto the SCALAR pipe via readfirstlane
//    (o, dg are wave-uniform): index loads become s_load, row gathers become
//    global_load_dwordx2 with SGPR row base + shared lane offset — 2 VGPRs
//    per in-flight gather, so 8 stay in flight. Batches padded to 8 (padded
//    loads read valid next-segment indices; adds predicated, strict k order).
//    Summation order IDENTICAL to rounds 3/5/7: self first, then csr order.
__global__ __launch_bounds__(256) void k_pull1(
    const int* __restrict__ off, const int* __restrict__ deg,
    const int* __restrict__ csr, const float* __restrict__ Y1,
    const float* __restrict__ dinv, const float* __restrict__ b1,
    float* __restrict__ Z, float* __restrict__ colsum,
    float* __restrict__ colsumsq) {
  __shared__ float s_sum[4][128], s_sq[4][128];
  int t = threadIdx.x, lane = t & 63, wid = t >> 6;
  const float2* Y = (const float2*)Y1;
  float bx = b1[2 * lane], by = b1[2 * lane + 1];
  float sx = 0.f, sy = 0.f, qx = 0.f, qy = 0.f;
  int n0 = blockIdx.x * 16 + wid * 4;
  for (int u = 0; u < 4; ++u) {
    int n = n0 + u;                      // NN = 3125*16, no tail
    float2 acc = Y[(size_t)n * 64 + lane];   // self loop FIRST (order matters)
    int o  = __builtin_amdgcn_readfirstlane(off[n]);
    int dg = __builtin_amdgcn_readfirstlane(deg[n]);
    for (int kb = 0; kb < dg; kb += 8) {
      // 8 scalar index loads (uniform SGPR address -> s_load path)
      int s0 = csr[o + kb + 0], s1 = csr[o + kb + 1];
      int s2 = csr[o + kb + 2], s3 = csr[o + kb + 3];
      int s4 = csr[o + kb + 4], s5 = csr[o + kb + 5];
      int s6 = csr[o + kb + 6], s7 = csr[o + kb + 7];
      // 8 row gathers, SGPR base + lane offset, all in flight
      float2 y0 = Y[(size_t)s0 * 64 + lane];
      float2 y1 = Y[(size_t)s1 * 64 + lane];
      float2 y2 = Y[(size_t)s2 * 64 + lane];
      float2 y3 = Y[(size_t)s3 * 64 + lane];
      float2 y4 = Y[(size_t)s4 * 64 + lane];
      float2 y5 = Y[(size_t)s5 * 64 + lane];
      float2 y6 = Y[(size_t)s6 * 64 + lane];
      float2 y7 = Y[(size_t)s7 * 64 + lane];
      // predicated adds, strictly ascending k (wave-uniform conditions)
      if (kb + 0 < dg) { acc.x += y0.x; acc.y += y0.y; }
      if (kb + 1 < dg) { acc.x += y1.x; acc.y += y1.y; }
      if (kb + 2 < dg) { acc.x += y2.x; acc.y += y2.y; }
      if (kb + 3 < dg) { acc.x += y3.x; acc.y += y3.y; }
      if (kb + 4 < dg) { acc.x += y4.x; acc.y += y4.y; }
      if (kb + 5 < dg) { acc.x += y5.x; acc.y += y5.y; }
      if (kb + 6 < dg) { acc.x += y6.x; acc.y += y6.y; }
      if (kb + 7 < dg) { acc.x += y7.x; acc.y += y7.y; }
    }
    float dn = dinv[n];
    float zx = fmaf(dn, acc.x, bx);
    float zy = fmaf(dn, acc.y, by);
    ((float2*)Z)[(size_t)n * 64 + lane] = make_float2(zx, zy);
    sx += zx; sy += zy; qx += zx * zx; qy += zy * zy;
  }
  s_sum[wid][2 * lane] = sx; s_sum[wid][2 * lane + 1] = sy;
  s_sq[wid][2 * lane]  = qx; s_sq[wid][2 * lane + 1]  = qy;
  __syncthreads();
  if (t < 128) {
    atomAddF(&colsum[t],   s_sum[0][t] + s_sum[1][t] + s_sum[2][t] + s_sum[3][t]);
    atomAddF(&colsumsq[t], s_sq[0][t] + s_sq[1][t] + s_sq[2][t] + s_sq[3][t]);
  }
}

// 6. BN scale/shift from raw moments (biased var, as torch BN)
__global__ void k_bn(const float* __restrict__ colsum, const float* __restrict__ colsumsq,
                     const float* __restrict__ gamma, const float* __restrict__ beta,
                     float* __restrict__ scale, float* __restrict__ shift) {
  int j = threadIdx.x;
  float mean = colsum[j] * (1.0f / NN);
  float var  = colsumsq[j] * (1.0f / NN) - mean * mean;
  float sc = gamma[j] * rsqrtf(var + BN_EPS);
  scale[j] = sc;
  shift[j] = beta[j] - mean * sc;
}

// 7. Y2[i][j] = dinv[i] * sum_k relu(Z[i][k]*scale[k]+shift[k]) * W2[k][j]
//    register-blocked 4 rows x 4 cols; BN+ReLU fused into the k-loop.
__global__ __launch_bounds__(256) void k_gemm2(const float* __restrict__ Z,
                                               const float* __restrict__ W2,
                                               const float* __restrict__ scale,
                                               const float* __restrict__ shift,
                                               const float* __restrict__ dinv,
                                               float* __restrict__ Y2) {
  int t = threadIdx.x;
  if (t >= 250) return;
  int tx = t % 10;          // col quad 0..9 -> c0 = tx*4 (DOUT=40)
  int ty = t / 10;          // 0..24 -> 4 rows each -> 100 rows/block
  int r0 = blockIdx.x * 100 + ty * 4;   // grid=500 -> exactly 50000 rows
  int c0 = tx * 4;
  const float4* W4  = (const float4*)W2;     // quad index = k*10 + tx
  const float4* sc4 = (const float4*)scale;
  const float4* sh4 = (const float4*)shift;

  const float* zp[4];
#pragma unroll
  for (int r = 0; r < 4; ++r) zp[r] = Z + (size_t)(r0 + r) * DH;

  float acc[4][4] = {};
  for (int k4 = 0; k4 < DH / 4; ++k4) {
    int k = k4 * 4;
    float4 sc = sc4[k4], sh = sh4[k4];
    float4 w0 = W4[(k + 0) * 10 + tx];
    float4 w1 = W4[(k + 1) * 10 + tx];
    float4 w2 = W4[(k + 2) * 10 + tx];
    float4 w3 = W4[(k + 3) * 10 + tx];
#pragma unroll
    for (int r = 0; r < 4; ++r) {
      float4 zv = *(const float4*)(zp[r] + k);
      float x0 = fmaxf(fmaf(zv.x, sc.x, sh.x), 0.f);
      float x1 = fmaxf(fmaf(zv.y, sc.y, sh.y), 0.f);
      float x2 = fmaxf(fmaf(zv.z, sc.z, sh.z), 0.f);
      float x3 = fmaxf(fmaf(zv.w, sc.w, sh.w), 0.f);
      acc[r][0] = fmaf(x0, w0.x, fmaf(x1, w1.x, fmaf(x2, w2.x, fmaf(x3, w3.x, acc[r][0]))));
      acc[r][1] = fmaf(x0, w0.y, fmaf(x1, w1.y, fmaf(x2, w2.y, fmaf(x3, w3.y, acc[r][1]))));
      acc[r][2] = fmaf(x0, w0.z, fmaf(x1, w1.z, fmaf(x2, w2.z, fmaf(x3, w3.z, acc[r][2]))));
      acc[r][3] = fmaf(x0, w0.w, fmaf(x1, w1.w, fmaf(x2, w2.w, fmaf(x3, w3.w, acc[r][3]))));
    }
  }
#pragma unroll
  for (int r = 0; r < 4; ++r) {
    int row = r0 + r;
    float dv = dinv[row];
    *(float4*)(Y2 + (size_t)row * DOUT + c0) =
        make_float4(acc[r][0] * dv, acc[r][1] * dv, acc[r][2] * dv, acc[r][3] * dv);
  }
}

// 8. pull-mode aggregation layer2, same scalar-pipe CSR walk + padded batch-8;
//    summation order as rounds 3/5/7 (self first, csr order); writes d_out.
__global__ __launch_bounds__(256) void k_pull2(
    const int* __restrict__ off, const int* __restrict__ deg,
    const int* __restrict__ csr, const float* __restrict__ Y2,
    const float* __restrict__ dinv, const float* __restrict__ b2,
    float* __restrict__ out) {
  int t = threadIdx.x, lane = t & 63, wid = t >> 6;
  bool act = lane < DOUT;
  float bv = act ? b2[lane] : 0.f;
  int lx = act ? lane : 0;               // safe column for inactive lanes
  int n0 = blockIdx.x * 16 + wid * 4;
  for (int u = 0; u < 4; ++u) {
    int n = n0 + u;
    float acc = act ? Y2[(size_t)n * DOUT + lane] : 0.f;   // self loop
    int o  = __builtin_amdgcn_readfirstlane(off[n]);
    int dg = __builtin_amdgcn_readfirstlane(deg[n]);
    for (int kb = 0; kb < dg; kb += 8) {
      int s0 = csr[o + kb + 0], s1 = csr[o + kb + 1];
      int s2 = csr[o + kb + 2], s3 = csr[o + kb + 3];
      int s4 = csr[o + kb + 4], s5 = csr[o + kb + 5];
      int s6 = csr[o + kb + 6], s7 = csr[o + kb + 7];
      float y0 = Y2[(size_t)s0 * DOUT + lx];
      float y1 = Y2[(size_t)s1 * DOUT + lx];
      float y2 = Y2[(size_t)s2 * DOUT + lx];
      float y3 = Y2[(size_t)s3 * DOUT + lx];
      float y4 = Y2[(size_t)s4 * DOUT + lx];
      float y5 = Y2[(size_t)s5 * DOUT + lx];
      float y6 = Y2[(size_t)s6 * DOUT + lx];
      float y7 = Y2[(size_t)s7 * DOUT + lx];
      if (kb + 0 < dg) acc += y0;
      if (kb + 1 < dg) acc += y1;
      if (kb + 2 < dg) acc += y2;
      if (kb + 3 < dg) acc += y3;
      if (kb + 4 < dg) acc += y4;
      if (kb + 5 < dg) acc += y5;
      if (kb + 6 < dg) acc += y6;
      if (kb + 7 < dg) acc += y7;
    }
    if (act) out[(size_t)n * DOUT + lane] = fmaf(dinv[n], acc, bv);
  }
}

extern "C" void kernel_launch(void* const* d_in, const int* in_sizes, int n_in,
                              void* d_out, int out_size, void* d_ws, size_t ws_size,
                              hipStream_t stream) {
  const float* X     = (const float*)d_in[0];
  const float* W1    = (const float*)d_in[1];
  const float* b1    = (const float*)d_in[2];
  const float* gamma = (const float*)d_in[3];
  const float* beta  = (const float*)d_in[4];
  const float* W2    = (const float*)d_in[5];
  const float* b2    = (const float*)d_in[6];
  const int*   edges = (const int*)d_in[7];
  int E = in_sizes[7] / 2;
  const int* src = edges;
  const int* dst = edges + E;

  int E8 = ((E + 7) & ~7) + 8;               // pad so batch-8 over-reads stay in-bounds
  int* i_deg = (int*)d_ws;                   // NN (int), stride 50048
  int* i_off = i_deg + 50048;
  int* i_cur = i_off + 50048;
  int* i_cnt = i_cur + 50016;                // counter in i_cur's padding
  int* i_csr = i_cur + 50048;                // E (+pad)
  float* f_dinv = (float*)(i_csr + E8);      // NN
  float* f_Y1   = f_dinv + 50048;            // NN*DH ; reused as Y2 after pull1
  float* f_Z    = f_Y1 + (size_t)NN * DH;    // NN*DH
  float* f_st   = f_Z + (size_t)NN * DH;     // colsum|colsumsq|scale|shift (4*128)
  float* f_Y2   = f_Y1;                      // alias: Y1 dead after k_pull1

  hipMemsetAsync(i_deg, 0, 50000 * sizeof(int), stream);
  hipMemsetAsync(i_cnt, 0, sizeof(int), stream);
  hipMemsetAsync(i_csr + E, 0, (size_t)(E8 - E) * sizeof(int), stream); // csr pad -> row 0
  hipMemsetAsync(f_st, 0, 256 * sizeof(float), stream);

  k_deg <<<(E + 255) / 256, 256, 0, stream>>>(dst, i_deg, E);
  k_off <<<(NN + 255) / 256, 256, 0, stream>>>(i_deg, i_off, i_cur, f_dinv, i_cnt);
  k_fill<<<(E + 255) / 256, 256, 0, stream>>>(src, dst, i_cur, i_csr, E);
  k_gemm1<<<(NN + 63) / 64, 256, 0, stream>>>(X, W1, f_dinv, f_Y1);
  k_pull1<<<NN / 16, 256, 0, stream>>>(i_off, i_deg, i_csr, f_Y1, f_dinv, b1,
                                       f_Z, f_st, f_st + 128);
  k_bn<<<1, 128, 0, stream>>>(f_st, f_st + 128, gamma, beta, f_st + 256, f_st + 384);
  k_gemm2<<<500, 256, 0, stream>>>(f_Z, W2, f_st + 256, f_st + 384, f_dinv, f_Y2);
  k_pull2<<<NN / 16, 256, 0, stream>>>(i_off, i_deg, i_csr, f_Y2, f_dinv, b2,
                                       (float*)d_out);
}

// Round 10
// 380.061 us; speedup vs baseline: 1.0869x; 1.0869x over previous
//
#include <hip/hip_runtime.h>

#define NN 50000
#define DIN 128
#define DH  128
#define DOUT 40
#define BN_EPS 1e-5f

__device__ __forceinline__ void atomAddF(float* p, float v) {
  unsafeAtomicAdd(p, v);   // native global_atomic_add_f32 on gfx950
}

// bf16 storage helpers (RNE), fp32 accumulation everywhere.
__device__ __forceinline__ unsigned short f2bf(float f) {
  unsigned int u = __float_as_uint(f);
  return (unsigned short)((u + 0x7FFFu + ((u >> 16) & 1u)) >> 16);
}
__device__ __forceinline__ float bflo(unsigned int u) {   // low ushort -> float
  return __uint_as_float(u << 16);
}
__device__ __forceinline__ float bfhi(unsigned int u) {   // high ushort -> float
  return __uint_as_float(u & 0xFFFF0000u);
}
__device__ __forceinline__ float bf1(unsigned short h) {
  return __uint_as_float(((unsigned int)h) << 16);
}

// 1. int in-degree histogram over dst (self-loop folded in later)
__global__ void k_deg(const int* __restrict__ dst, int* __restrict__ deg, int E) {
  int e = blockIdx.x * blockDim.x + threadIdx.x;
  if (e < E) atomicAdd(&deg[dst[e]], 1);
}

// 2. CSR offsets via wave-aggregated atomic counter (order-free, scan-free).
__global__ void k_off(const int* __restrict__ deg, int* __restrict__ off,
                      int* __restrict__ cur, float* __restrict__ dinv,
                      int* __restrict__ counter) {
  int i = blockIdx.x * 256 + threadIdx.x;
  int lane = threadIdx.x & 63;
  int d = (i < NN) ? deg[i] : 0;
  int pre = d;
#pragma unroll
  for (int o = 1; o < 64; o <<= 1) {
    int v = __shfl_up(pre, o);
    if (lane >= o) pre += v;
  }
  int tot = __shfl(pre, 63);            // wave total
  int base = 0;
  if (lane == 63) base = atomicAdd(counter, tot);
  base = __shfl(base, 63);
  int o0 = base + pre - d;              // exclusive within wave
  if (i < NN) {
    off[i] = o0; cur[i] = o0;
    dinv[i] = rsqrtf((float)d + 1.0f);
  }
}

// 3. CSR fill: group src indices by dst
__global__ void k_fill(const int* __restrict__ src, const int* __restrict__ dst,
                       int* __restrict__ cur, int* __restrict__ csr, int E) {
  int e = blockIdx.x * blockDim.x + threadIdx.x;
  if (e >= E) return;
  int pos = atomicAdd(&cur[dst[e]], 1);
  csr[pos] = src[e];
}

// 4. Y1[i][j] = bf16( dinv[i] * sum_k X[i][k] * W1[k][j] )
//    register-blocked 8x4; fp32 math, bf16 store (halves gather bytes).
__global__ __launch_bounds__(256) void k_gemm1(const float* __restrict__ X,
                                               const float* __restrict__ W,
                                               const float* __restrict__ dinv,
                                               unsigned short* __restrict__ Y) {
  int t = threadIdx.x;
  int tx = t & 31;          // col quad 0..31 -> c0 = tx*4
  int ty = t >> 5;          // 0..7 -> 8 rows each
  int r0 = blockIdx.x * 64 + ty * 8;
  int c0 = tx * 4;
  const float4* W4 = (const float4*)W;   // quad index = k*32 + tx

  const float* xp[8];
#pragma unroll
  for (int r = 0; r < 8; ++r) {
    int row = r0 + r;
    if (row >= NN) row = NN - 1;         // clamp: safe load, store guarded
    xp[r] = X + (size_t)row * DIN;
  }

  float acc[8][4] = {};
  for (int k = 0; k < DIN; k += 4) {
    float4 w0 = W4[(k + 0) * 32 + tx];
    float4 w1 = W4[(k + 1) * 32 + tx];
    float4 w2 = W4[(k + 2) * 32 + tx];
    float4 w3 = W4[(k + 3) * 32 + tx];
#pragma unroll
    for (int r = 0; r < 8; ++r) {
      float4 xv = *(const float4*)(xp[r] + k);
      acc[r][0] = fmaf(xv.x, w0.x, fmaf(xv.y, w1.x, fmaf(xv.z, w2.x, fmaf(xv.w, w3.x, acc[r][0]))));
      acc[r][1] = fmaf(xv.x, w0.y, fmaf(xv.y, w1.y, fmaf(xv.z, w2.y, fmaf(xv.w, w3.y, acc[r][1]))));
      acc[r][2] = fmaf(xv.x, w0.z, fmaf(xv.y, w1.z, fmaf(xv.z, w2.z, fmaf(xv.w, w3.z, acc[r][2]))));
      acc[r][3] = fmaf(xv.x, w0.w, fmaf(xv.y, w1.w, fmaf(xv.z, w2.w, fmaf(xv.w, w3.w, acc[r][3]))));
    }
  }
#pragma unroll
  for (int r = 0; r < 8; ++r) {
    int row = r0 + r;
    if (row < NN) {
      float dv = dinv[row];
      ushort4 st;
      st.x = f2bf(acc[r][0] * dv); st.y = f2bf(acc[r][1] * dv);
      st.z = f2bf(acc[r][2] * dv); st.w = f2bf(acc[r][3] * dv);
      *(ushort4*)(Y + (size_t)row * DH + c0) = st;
    }
  }
}

// 5. pull-mode aggregation layer1 + finalize + fused BN column stats.
//    Wave per node, 2 bf16 cols per lane (one uint). CSR walk on the scalar
//    pipe (readfirstlane -> s_load indices, SGPR-base row gathers). Batch-8
//    full batches (unconditional adds), serial tail — no wasted gathers.
//    Accumulation fp32; order: self first, then neighbors in csr order.
__global__ __launch_bounds__(256) void k_pull1(
    const int* __restrict__ off, const int* __restrict__ deg,
    const int* __restrict__ csr, const unsigned int* __restrict__ Yu,
    const float* __restrict__ dinv, const float* __restrict__ b1,
    float* __restrict__ Z, float* __restrict__ colsum,
    float* __restrict__ colsumsq) {
  __shared__ float s_sum[4][128], s_sq[4][128];
  int t = threadIdx.x, lane = t & 63, wid = t >> 6;
  float bx = b1[2 * lane], by = b1[2 * lane + 1];
  float sx = 0.f, sy = 0.f, qx = 0.f, qy = 0.f;
  int n0 = blockIdx.x * 16 + wid * 4;
  for (int u = 0; u < 4; ++u) {
    int n = n0 + u;                      // NN = 3125*16, no tail
    unsigned int us = Yu[(size_t)n * 64 + lane];   // self loop FIRST
    float2 acc = make_float2(bflo(us), bfhi(us));
    int o  = __builtin_amdgcn_readfirstlane(off[n]);
    int dg = __builtin_amdgcn_readfirstlane(deg[n]);
    int kb = 0;
    for (; kb + 8 <= dg; kb += 8) {
      int s0 = csr[o + kb + 0], s1 = csr[o + kb + 1];
      int s2 = csr[o + kb + 2], s3 = csr[o + kb + 3];
      int s4 = csr[o + kb + 4], s5 = csr[o + kb + 5];
      int s6 = csr[o + kb + 6], s7 = csr[o + kb + 7];
      unsigned int y0 = Yu[(size_t)s0 * 64 + lane];
      unsigned int y1 = Yu[(size_t)s1 * 64 + lane];
      unsigned int y2 = Yu[(size_t)s2 * 64 + lane];
      unsigned int y3 = Yu[(size_t)s3 * 64 + lane];
      unsigned int y4 = Yu[(size_t)s4 * 64 + lane];
      unsigned int y5 = Yu[(size_t)s5 * 64 + lane];
      unsigned int y6 = Yu[(size_t)s6 * 64 + lane];
      unsigned int y7 = Yu[(size_t)s7 * 64 + lane];
      acc.x += bflo(y0); acc.y += bfhi(y0);   // strict k order
      acc.x += bflo(y1); acc.y += bfhi(y1);
      acc.x += bflo(y2); acc.y += bfhi(y2);
      acc.x += bflo(y3); acc.y += bfhi(y3);
      acc.x += bflo(y4); acc.y += bfhi(y4);
      acc.x += bflo(y5); acc.y += bfhi(y5);
      acc.x += bflo(y6); acc.y += bfhi(y6);
      acc.x += bflo(y7); acc.y += bfhi(y7);
    }
    for (int k = kb; k < dg; ++k) {            // serial tail (<=7)
      int sN = csr[o + k];
      unsigned int y = Yu[(size_t)sN * 64 + lane];
      acc.x += bflo(y); acc.y += bfhi(y);
    }
    float dn = dinv[n];
    float zx = fmaf(dn, acc.x, bx);
    float zy = fmaf(dn, acc.y, by);
    ((float2*)Z)[(size_t)n * 64 + lane] = make_float2(zx, zy);
    sx += zx; sy += zy; qx += zx * zx; qy += zy * zy;
  }
  s_sum[wid][2 * lane] = sx; s_sum[wid][2 * lane + 1] = sy;
  s_sq[wid][2 * lane]  = qx; s_sq[wid][2 * lane + 1]  = qy;
  __syncthreads();
  if (t < 128) {
    atomAddF(&colsum[t],   s_sum[0][t] + s_sum[1][t] + s_sum[2][t] + s_sum[3][t]);
    atomAddF(&colsumsq[t], s_sq[0][t] + s_sq[1][t] + s_sq[2][t] + s_sq[3][t]);
  }
}

// 6. BN scale/shift from raw moments (biased var, as torch BN)
__global__ void k_bn(const float* __restrict__ colsum, const float* __restrict__ colsumsq,
                     const float* __restrict__ gamma, const float* __restrict__ beta,
                     float* __restrict__ scale, float* __restrict__ shift) {
  int j = threadIdx.x;
  float mean = colsum[j] * (1.0f / NN);
  float var  = colsumsq[j] * (1.0f / NN) - mean * mean;
  float sc = gamma[j] * rsqrtf(var + BN_EPS);
  scale[j] = sc;
  shift[j] = beta[j] - mean * sc;
}

// 7. Y2[i][j] = bf16( dinv[i] * sum_k relu(Z[i][k]*scale[k]+shift[k]) * W2[k][j] )
//    register-blocked 4x4; BN+ReLU fused; fp32 math, bf16 store.
__global__ __launch_bounds__(256) void k_gemm2(const float* __restrict__ Z,
                                               const float* __restrict__ W2,
                                               const float* __restrict__ scale,
                                               const float* __restrict__ shift,
                                               const float* __restrict__ dinv,
                                               unsigned short* __restrict__ Y2) {
  int t = threadIdx.x;
  if (t >= 250) return;
  int tx = t % 10;          // col quad 0..9 -> c0 = tx*4 (DOUT=40)
  int ty = t / 10;          // 0..24 -> 4 rows each -> 100 rows/block
  int r0 = blockIdx.x * 100 + ty * 4;   // grid=500 -> exactly 50000 rows
  int c0 = tx * 4;
  const float4* W4  = (const float4*)W2;     // quad index = k*10 + tx
  const float4* sc4 = (const float4*)scale;
  const float4* sh4 = (const float4*)shift;

  const float* zp[4];
#pragma unroll
  for (int r = 0; r < 4; ++r) zp[r] = Z + (size_t)(r0 + r) * DH;

  float acc[4][4] = {};
  for (int k4 = 0; k4 < DH / 4; ++k4) {
    int k = k4 * 4;
    float4 sc = sc4[k4], sh = sh4[k4];
    float4 w0 = W4[(k + 0) * 10 + tx];
    float4 w1 = W4[(k + 1) * 10 + tx];
    float4 w2 = W4[(k + 2) * 10 + tx];
    float4 w3 = W4[(k + 3) * 10 + tx];
#pragma unroll
    for (int r = 0; r < 4; ++r) {
      float4 zv = *(const float4*)(zp[r] + k);
      float x0 = fmaxf(fmaf(zv.x, sc.x, sh.x), 0.f);
      float x1 = fmaxf(fmaf(zv.y, sc.y, sh.y), 0.f);
      float x2 = fmaxf(fmaf(zv.z, sc.z, sh.z), 0.f);
      float x3 = fmaxf(fmaf(zv.w, sc.w, sh.w), 0.f);
      acc[r][0] = fmaf(x0, w0.x, fmaf(x1, w1.x, fmaf(x2, w2.x, fmaf(x3, w3.x, acc[r][0]))));
      acc[r][1] = fmaf(x0, w0.y, fmaf(x1, w1.y, fmaf(x2, w2.y, fmaf(x3, w3.y, acc[r][1]))));
      acc[r][2] = fmaf(x0, w0.z, fmaf(x1, w1.z, fmaf(x2, w2.z, fmaf(x3, w3.z, acc[r][2]))));
      acc[r][3] = fmaf(x0, w0.w, fmaf(x1, w1.w, fmaf(x2, w2.w, fmaf(x3, w3.w, acc[r][3]))));
    }
  }
#pragma unroll
  for (int r = 0; r < 4; ++r) {
    int row = r0 + r;
    float dv = dinv[row];
    ushort4 st;
    st.x = f2bf(acc[r][0] * dv); st.y = f2bf(acc[r][1] * dv);
    st.z = f2bf(acc[r][2] * dv); st.w = f2bf(acc[r][3] * dv);
    *(ushort4*)(Y2 + (size_t)row * DOUT + c0) = st;
  }
}

// 8. pull-mode aggregation layer2 (bf16 rows, 80B), scalar CSR walk,
//    batch-8 + serial tail; fp32 accumulate; writes fp32 d_out.
__global__ __launch_bounds__(256) void k_pull2(
    const int* __restrict__ off, const int* __restrict__ deg,
    const int* __restrict__ csr, const unsigned short* __restrict__ Y2,
    const float* __restrict__ dinv, const float* __restrict__ b2,
    float* __restrict__ out) {
  int t = threadIdx.x, lane = t & 63, wid = t >> 6;
  bool act = lane < DOUT;
  float bv = act ? b2[lane] : 0.f;
  int lx = act ? lane : 0;               // safe column for inactive lanes
  int n0 = blockIdx.x * 16 + wid * 4;
  for (int u = 0; u < 4; ++u) {
    int n = n0 + u;
    float acc = bf1(Y2[(size_t)n * DOUT + lx]);   // self loop first
    int o  = __builtin_amdgcn_readfirstlane(off[n]);
    int dg = __builtin_amdgcn_readfirstlane(deg[n]);
    int kb = 0;
    for (; kb + 8 <= dg; kb += 8) {
      int s0 = csr[o + kb + 0], s1 = csr[o + kb + 1];
      int s2 = csr[o + kb + 2], s3 = csr[o + kb + 3];
      int s4 = csr[o + kb + 4], s5 = csr[o + kb + 5];
      int s6 = csr[o + kb + 6], s7 = csr[o + kb + 7];
      unsigned short y0 = Y2[(size_t)s0 * DOUT + lx];
      unsigned short y1 = Y2[(size_t)s1 * DOUT + lx];
      unsigned short y2 = Y2[(size_t)s2 * DOUT + lx];
      unsigned short y3 = Y2[(size_t)s3 * DOUT + lx];
      unsigned short y4 = Y2[(size_t)s4 * DOUT + lx];
      unsigned short y5 = Y2[(size_t)s5 * DOUT + lx];
      unsigned short y6 = Y2[(size_t)s6 * DOUT + lx];
      unsigned short y7 = Y2[(size_t)s7 * DOUT + lx];
      acc += bf1(y0); acc += bf1(y1); acc += bf1(y2); acc += bf1(y3);
      acc += bf1(y4); acc += bf1(y5); acc += bf1(y6); acc += bf1(y7);
    }
    for (int k = kb; k < dg; ++k) {
      int sN = csr[o + k];
      acc += bf1(Y2[(size_t)sN * DOUT + lx]);
    }
    if (act) out[(size_t)n * DOUT + lane] = fmaf(dinv[n], acc, bv);
  }
}

extern "C" void kernel_launch(void* const* d_in, const int* in_sizes, int n_in,
                              void* d_out, int out_size, void* d_ws, size_t ws_size,
                              hipStream_t stream) {
  const float* X     = (const float*)d_in[0];
  const float* W1    = (const float*)d_in[1];
  const float* b1    = (const float*)d_in[2];
  const float* gamma = (const float*)d_in[3];
  const float* beta  = (const float*)d_in[4];
  const float* W2    = (const float*)d_in[5];
  const float* b2    = (const float*)d_in[6];
  const int*   edges = (const int*)d_in[7];
  int E = in_sizes[7] / 2;
  const int* src = edges;
  const int* dst = edges + E;

  int E4 = (E + 3) & ~3;                         // 16B-align following region
  int* i_deg = (int*)d_ws;                       // NN ints, stride 50048
  int* i_off = i_deg + 50048;
  int* i_cur = i_off + 50048;
  int* i_cnt = i_cur + 50016;                    // counter in i_cur's padding
  int* i_csr = i_cur + 50048;                    // E ints
  float* f_dinv = (float*)(i_csr + E4);          // NN floats
  unsigned short* u_Y1 = (unsigned short*)(f_dinv + 50048);   // NN*DH bf16
  float* f_Z  = (float*)(u_Y1 + (size_t)NN * DH);             // NN*DH fp32
  float* f_st = f_Z + (size_t)NN * DH;           // colsum|colsumsq|scale|shift
  unsigned short* u_Y2 = u_Y1;                   // alias: Y1 dead after k_pull1

  hipMemsetAsync(i_deg, 0, 50000 * sizeof(int), stream);
  hipMemsetAsync(i_cnt, 0, sizeof(int), stream);
  hipMemsetAsync(f_st, 0, 256 * sizeof(float), stream);

  k_deg <<<(E + 255) / 256, 256, 0, stream>>>(dst, i_deg, E);
  k_off <<<(NN + 255) / 256, 256, 0, stream>>>(i_deg, i_off, i_cur, f_dinv, i_cnt);
  k_fill<<<(E + 255) / 256, 256, 0, stream>>>(src, dst, i_cur, i_csr, E);
  k_gemm1<<<(NN + 63) / 64, 256, 0, stream>>>(X, W1, f_dinv, u_Y1);
  k_pull1<<<NN / 16, 256, 0, stream>>>(i_off, i_deg, i_csr,
                                       (const unsigned int*)u_Y1, f_dinv, b1,
                                       f_Z, f_st, f_st + 128);
  k_bn<<<1, 128, 0, stream>>>(f_st, f_st + 128, gamma, beta, f_st + 256, f_st + 384);
  k_gemm2<<<500, 256, 0, stream>>>(f_Z, W2, f_st + 256, f_st + 384, f_dinv, u_Y2);
  k_pull2<<<NN / 16, 256, 0, stream>>>(i_off, i_deg, i_csr, u_Y2, f_dinv, b2,
                                       (float*)d_out);
}